// Round 1
// baseline (9692.331 us; speedup 1.0000x reference)
//
#include <hip/hip_runtime.h>
#include <math.h>

#define HIDN 512
#define H3 1536
#define BSZN 4096
#define CNUM 4
#define NHEAD 8
#define LNUM 4
#define OUTN 32000

// =====================================================================
// GEMM: C[m][n] (+)= sum_k (A[m][k] + ids[c][k]) * B[c][n][k] + bias[c][n]
//   A: (M,K) row-major, lda=K.  B: per-c (N,K) row-major (weight layout).
//   c = row / rows_per_c (blocks never straddle c groups: rows_per_c % 64 == 0).
//   ldc: C row stride (may exceed N).  accum: += instead of =.
// fp32, 64x64 tile, 256 thr, 4x4 per thread. Round-0 correctness-first.
// =====================================================================
__global__ __launch_bounds__(256) void gemm_bt(
    const float* __restrict__ A, const float* __restrict__ B,
    const float* __restrict__ bias, const float* __restrict__ ids,
    float* __restrict__ C, int M, int N, int K, int ldc,
    long sBc, long sBias, long sIds, int rows_per_c, int accum)
{
    __shared__ float As[16][65];
    __shared__ float Bs[16][65];
    int tid = threadIdx.x;
    int tx = tid & 15, ty = tid >> 4;
    int row0 = blockIdx.y * 64, col0 = blockIdx.x * 64;
    int c = row0 / rows_per_c;
    const float* Bc    = B + (long)c * sBc;
    const float* biasc = bias + (long)c * sBias;
    const float* idsc  = ids ? (ids + (long)c * sIds) : nullptr;

    int lm = tid >> 2;          // 0..63
    int lk = (tid & 3) << 2;    // 0,4,8,12
    const float* Aptr = A  + (long)(row0 + lm) * K + lk;
    const float* Bptr = Bc + (long)(col0 + lm) * K + lk;

    float acc[4][4] = {};
    for (int k0 = 0; k0 < K; k0 += 16) {
        float4 av = *(const float4*)(Aptr + k0);
        if (idsc) {
            float4 iv = *(const float4*)(idsc + k0 + lk);
            av.x += iv.x; av.y += iv.y; av.z += iv.z; av.w += iv.w;
        }
        As[lk+0][lm] = av.x; As[lk+1][lm] = av.y;
        As[lk+2][lm] = av.z; As[lk+3][lm] = av.w;
        float4 bv = *(const float4*)(Bptr + k0);
        Bs[lk+0][lm] = bv.x; Bs[lk+1][lm] = bv.y;
        Bs[lk+2][lm] = bv.z; Bs[lk+3][lm] = bv.w;
        __syncthreads();
        #pragma unroll
        for (int kk = 0; kk < 16; ++kk) {
            float a[4], b[4];
            #pragma unroll
            for (int i = 0; i < 4; ++i) a[i] = As[kk][ty*4+i];
            #pragma unroll
            for (int j = 0; j < 4; ++j) b[j] = Bs[kk][tx*4+j];
            #pragma unroll
            for (int i = 0; i < 4; ++i)
                #pragma unroll
                for (int j = 0; j < 4; ++j)
                    acc[i][j] += a[i] * b[j];
        }
        __syncthreads();
    }
    #pragma unroll
    for (int i = 0; i < 4; ++i) {
        int r = row0 + ty*4 + i;
        #pragma unroll
        for (int j = 0; j < 4; ++j) {
            int cl = col0 + tx*4 + j;
            float v = acc[i][j] + biasc[cl];
            long off = (long)r * ldc + cl;
            if (accum) C[off] += v; else C[off] = v;
        }
    }
}

// ---------------- embedding lookup: x[b][e] = emb[tokens[b]][e]
__global__ void embed_k(const int* __restrict__ tokens, const float* __restrict__ emb,
                        float* __restrict__ x, int total)
{
    int idx = blockIdx.x * blockDim.x + threadIdx.x;
    if (idx >= total) return;
    int b = idx >> 9, e = idx & 511;
    x[idx] = emb[(long)tokens[b] * HIDN + e];
}

// ---------------- fill gx rows with per-c bias (l=0, c>=1: dummy x is zero)
__global__ void fill_bias_k(float* __restrict__ dst, const float* __restrict__ bias,
                            int N, long sBias, int rows_per_c, int total)
{
    int idx = blockIdx.x * blockDim.x + threadIdx.x;
    if (idx >= total) return;
    int r = idx / N, col = idx % N;
    int c = r / rows_per_c;
    dst[idx] = bias[(long)c * sBias + col];
}

// ---------------- GRU gates.
// S: (rows,1536): [xr+hr | xz+hz | xn].  Hn: (rows,512) = hn.  hp: previous h.
__global__ void gru_gates_k(const float* __restrict__ S, const float* __restrict__ Hn,
                            const float* __restrict__ hp, float* __restrict__ hout,
                            int total)
{
    int idx = blockIdx.x * blockDim.x + threadIdx.x;
    if (idx >= total) return;
    int row = idx >> 9, hcol = idx & 511;
    long base = (long)row * H3;
    float rr = S[base + hcol];
    float zz = S[base + HIDN + hcol];
    float xn = S[base + 2*HIDN + hcol];
    float hn = Hn[idx];
    float r = 1.f / (1.f + expf(-rr));
    float z = 1.f / (1.f + expf(-zz));
    float n = tanhf(xn + r * hn);
    hout[idx] = (1.f - z) * n + z * hp[idx];
}

// ---------------- attention over C=4: one wave per (b, head)
// qkbuf: (C*BSZ, 1024) = [q|k].  vbuf: (C*BSZ, 512).  obuf: (C*BSZ, 512).
__global__ __launch_bounds__(256) void attn_k(const float* __restrict__ qkbuf,
                                              const float* __restrict__ vbuf,
                                              float* __restrict__ obuf)
{
    int wave = (blockIdx.x * blockDim.x + threadIdx.x) >> 6;
    int lane = threadIdx.x & 63;
    int b = wave >> 3, n = wave & 7;          // 4096 x 8 waves
    float qv[4], kv[4], vv[4];
    #pragma unroll
    for (int c = 0; c < 4; ++c) {
        long rqk = (long)(c * BSZN + b) * 1024 + n * 64 + lane;
        qv[c] = qkbuf[rqk];
        kv[c] = qkbuf[rqk + 512];
        vv[c] = vbuf[(long)(c * BSZN + b) * 512 + n * 64 + lane];
    }
    float s[4][4];
    #pragma unroll
    for (int qi = 0; qi < 4; ++qi)
        #pragma unroll
        for (int ki = 0; ki < 4; ++ki) {
            float p = qv[qi] * kv[ki];
            #pragma unroll
            for (int off = 32; off; off >>= 1) p += __shfl_xor(p, off);
            s[qi][ki] = p * 0.125f;           // 1/sqrt(64)
        }
    #pragma unroll
    for (int qi = 0; qi < 4; ++qi) {
        float mx = fmaxf(fmaxf(s[qi][0], s[qi][1]), fmaxf(s[qi][2], s[qi][3]));
        float e0 = expf(s[qi][0]-mx), e1 = expf(s[qi][1]-mx);
        float e2 = expf(s[qi][2]-mx), e3 = expf(s[qi][3]-mx);
        float inv = 1.f / (e0 + e1 + e2 + e3);
        float ov = (e0*vv[0] + e1*vv[1] + e2*vv[2] + e3*vv[3]) * inv;
        obuf[(long)(qi * BSZN + b) * 512 + n * 64 + lane] = ov;
    }
}

// ---------------- fused LayerNorm + gate + residual mix: one wave per row (512 cols)
__global__ __launch_bounds__(256) void ln_gate_k(
    const float* __restrict__ msg_pre, const float* __restrict__ hln,
    const float* __restrict__ lng, const float* __restrict__ lnb,
    const float* __restrict__ gw, const float* __restrict__ gb,
    float* __restrict__ hn_out, int rows)
{
    int wave = (blockIdx.x * blockDim.x + threadIdx.x) >> 6;
    int lane = threadIdx.x & 63;
    if (wave >= rows) return;
    const float* mrow = msg_pre + (long)wave * 512;
    float m[8];
    float sum = 0.f;
    #pragma unroll
    for (int i = 0; i < 8; ++i) { m[i] = mrow[lane + i*64]; sum += m[i]; }
    #pragma unroll
    for (int off = 32; off; off >>= 1) sum += __shfl_xor(sum, off);
    float mu = sum * (1.f / 512.f);
    float sq = 0.f;
    #pragma unroll
    for (int i = 0; i < 8; ++i) { float d = m[i] - mu; sq += d * d; }
    #pragma unroll
    for (int off = 32; off; off >>= 1) sq += __shfl_xor(sq, off);
    float rstd = rsqrtf(sq * (1.f / 512.f) + 1e-5f);

    const float* hrow = hln + (long)wave * 512;
    float msg[8], h[8];
    float gdot = 0.f;
    #pragma unroll
    for (int i = 0; i < 8; ++i) {
        int col = lane + i * 64;
        msg[i] = (m[i] - mu) * rstd * lng[col] + lnb[col];
        h[i] = hrow[col];
        gdot += h[i] * gw[col] + msg[i] * gw[512 + col];
    }
    #pragma unroll
    for (int off = 32; off; off >>= 1) gdot += __shfl_xor(gdot, off);
    float g = 1.f / (1.f + expf(-(gdot + gb[0])));
    float* orow = hn_out + (long)wave * 512;
    #pragma unroll
    for (int i = 0; i < 8; ++i)
        orow[lane + i * 64] = (1.f - g) * h[i] + g * msg[i];
}

// =====================================================================
extern "C" void kernel_launch(void* const* d_in, const int* in_sizes, int n_in,
                              void* d_out, int out_size, void* d_ws, size_t ws_size,
                              hipStream_t stream)
{
    const int*   tokens   = (const int*)  d_in[0];
    const float* h_in     = (const float*)d_in[1];
    const float* emb      = (const float*)d_in[2];
    const float* W_ih_00  = (const float*)d_in[3];
    const float* W_hh_00  = (const float*)d_in[4];
    const float* b_ih_00  = (const float*)d_in[5];
    const float* b_hh_00  = (const float*)d_in[6];
    // d_in[7] = W_ih_0r: multiplied by zeros in the reference -> unused
    const float* W_hh_0r  = (const float*)d_in[8];
    const float* b_ih_0r  = (const float*)d_in[9];
    const float* b_hh_0r  = (const float*)d_in[10];
    const float* W_ih     = (const float*)d_in[11];
    const float* W_hh     = (const float*)d_in[12];
    const float* b_ih     = (const float*)d_in[13];
    const float* b_hh     = (const float*)d_in[14];
    const float* ids      = (const float*)d_in[15];
    const float* in_w     = (const float*)d_in[16];
    const float* in_b     = (const float*)d_in[17];
    const float* out_w    = (const float*)d_in[18];
    const float* out_b    = (const float*)d_in[19];
    const float* ln_g     = (const float*)d_in[20];
    const float* ln_b     = (const float*)d_in[21];
    const float* gate_w   = (const float*)d_in[22];
    const float* gate_b   = (const float*)d_in[23];
    const float* head_w   = (const float*)d_in[24];
    const float* head_b   = (const float*)d_in[25];

    float* y  = (float*)d_out;                       // (4096, 32000)
    float* hn = y + (long)BSZN * OUTN;               // (4, 4, 4096, 512)

    const long ROWS   = (long)CNUM * BSZN;           // 16384
    const long LAYER  = ROWS * HIDN;                 // 8388608 elems per layer of h
    float* S    = (float*)d_ws;                      // (16384,1536): rz-combined + xn
    float* Hn   = S   + ROWS * H3;                   // (16384,512): hn
    float* hln  = Hn  + LAYER;                       // (16384,512): pre-gate h
    float* xbuf = hln + LAYER;                       // (4096,512): embedded x
    float* qk   = S;                                 // (16384,1024) alias
    float* obuf = S + ROWS * 1024;                   // (16384,512) alias
    float* mpre = S;                                 // (16384,512) alias (qk done)
    float* vbuf = Hn;                                // (16384,512) alias

    const int BIG = 1 << 30;
    auto gemm = [&](const float* A, const float* B, const float* bias,
                    const float* idsp, float* C, int M, int N, int K, int ldc,
                    long sBc, long sBias, long sIds, int rpc, int accum) {
        dim3 grid(N / 64, M / 64);
        hipLaunchKernelGGL(gemm_bt, grid, dim3(256), 0, stream,
                           A, B, bias, idsp, C, M, N, K, ldc,
                           sBc, sBias, sIds, rpc, accum);
    };

    // ---- embedding
    hipLaunchKernelGGL(embed_k, dim3((BSZN * HIDN) / 256), dim3(256), 0, stream,
                       tokens, emb, xbuf, BSZN * HIDN);

    for (int l = 0; l < LNUM; ++l) {
        const float* hl  = h_in + (long)l * LAYER;
        const float* xin = (l == 0) ? nullptr : (hn + (long)(l - 1) * LAYER);

        if (l == 0) {
            // gx: col 0 from x, cols 1..3 are pure bias (dummy input is zero)
            gemm(xbuf, W_ih_00, b_ih_00, nullptr, S, BSZN, H3, HIDN, H3,
                 0, 0, 0, BIG, 0);
            int total = (CNUM - 1) * BSZN * H3;
            hipLaunchKernelGGL(fill_bias_k, dim3((total + 255) / 256), dim3(256), 0, stream,
                               S + (long)BSZN * H3, b_ih_0r, H3, (long)H3, BSZN, total);
            // gh r,z accumulate into S; gh n -> Hn.  c=0 weights differ from c>=1.
            gemm(hl, W_hh_00, b_hh_00, nullptr, S, BSZN, 1024, HIDN, H3,
                 0, 0, 0, BIG, 1);
            gemm(hl, W_hh_00 + 1024 * HIDN, b_hh_00 + 1024, nullptr, Hn,
                 BSZN, HIDN, HIDN, HIDN, 0, 0, 0, BIG, 0);
            gemm(hl + (long)BSZN * HIDN, W_hh_0r, b_hh_0r, nullptr,
                 S + (long)BSZN * H3, (CNUM - 1) * BSZN, 1024, HIDN, H3,
                 (long)H3 * HIDN, (long)H3, 0, BSZN, 1);
            gemm(hl + (long)BSZN * HIDN, W_hh_0r + 1024 * HIDN, b_hh_0r + 1024, nullptr,
                 Hn + (long)BSZN * HIDN, (CNUM - 1) * BSZN, HIDN, HIDN, HIDN,
                 (long)H3 * HIDN, (long)H3, 0, BSZN, 0);
        } else {
            const float* Wi = W_ih + (long)(l - 1) * CNUM * H3 * HIDN;
            const float* Wh = W_hh + (long)(l - 1) * CNUM * H3 * HIDN;
            const float* bi = b_ih + (long)(l - 1) * CNUM * H3;
            const float* bh = b_hh + (long)(l - 1) * CNUM * H3;
            gemm(xin, Wi, bi, nullptr, S, ROWS, H3, HIDN, H3,
                 (long)H3 * HIDN, (long)H3, 0, BSZN, 0);
            gemm(hl, Wh, bh, nullptr, S, ROWS, 1024, HIDN, H3,
                 (long)H3 * HIDN, (long)H3, 0, BSZN, 1);
            gemm(hl, Wh + 1024 * HIDN, bh + 1024, nullptr, Hn, ROWS, HIDN, HIDN, HIDN,
                 (long)H3 * HIDN, (long)H3, 0, BSZN, 0);
        }
        // gates -> hln (pre-gate h for this layer)
        hipLaunchKernelGGL(gru_gates_k, dim3((ROWS * HIDN) / 256), dim3(256), 0, stream,
                           S, Hn, hl, hln, (int)(ROWS * HIDN));

        // ---- MHA
        const float* Wi_l = in_w + (long)l * H3 * HIDN;
        const float* bi_l = in_b + (long)l * H3;
        // q|k projection (input = hln + ids[l][c]) -> qk (aliases S; gates done)
        gemm(hln, Wi_l, bi_l, ids + (long)l * CNUM * HIDN, qk,
             ROWS, 1024, HIDN, 1024, 0, 0, (long)HIDN, BSZN, 0);
        // v projection (input = hln, no ids) -> vbuf (aliases Hn; gates done)
        gemm(hln, Wi_l + 1024 * HIDN, bi_l + 1024, nullptr, vbuf,
             ROWS, HIDN, HIDN, HIDN, 0, 0, 0, BIG, 0);
        // attention (C=4) -> obuf
        hipLaunchKernelGGL(attn_k, dim3((BSZN * NHEAD * 64) / 256), dim3(256), 0, stream,
                           qk, vbuf, obuf);
        // msg_pre = obuf @ Wo^T + bo  -> mpre (aliases qk region; qk consumed)
        gemm(obuf, out_w + (long)l * HIDN * HIDN, out_b + (long)l * HIDN, nullptr,
             mpre, ROWS, HIDN, HIDN, HIDN, 0, 0, 0, BIG, 0);
        // LN + gate + mix -> hn[l]
        hipLaunchKernelGGL(ln_gate_k, dim3((ROWS * 64) / 256), dim3(256), 0, stream,
                           mpre, hln, ln_g + (long)l * HIDN, ln_b + (long)l * HIDN,
                           gate_w + (long)l * 2 * HIDN, gate_b + l,
                           hn + (long)l * LAYER, (int)ROWS);
    }

    // ---- head: y = h_n[3][0] @ head_w^T + head_b
    gemm(hn + 3L * LAYER, head_w, head_b, nullptr, y,
         BSZN, OUTN, HIDN, OUTN, 0, 0, 0, BIG, 0);
}